// Round 3
// baseline (250.234 us; speedup 1.0000x reference)
//
#include <hip/hip_runtime.h>
#include <hip/hip_bf16.h>

#define B_DIM 32
#define N_IN 1000000
#define N_OUT 500000

typedef float nfloat4 __attribute__((ext_vector_type(4)));

__device__ __forceinline__ unsigned int f32_to_bf16_rne(float f) {
    unsigned int u = __float_as_uint(f);
    unsigned int rounding = 0x7fffu + ((u >> 16) & 1u);
    return (u + rounding) >> 16;   // low 16 bits = bf16
}

// ---------- Kernel 1 v2: transpose+downconvert, 256 cols/block ---------------
// Each wave reads 1KB contiguous per row-stream (vs 256B in v1) and keeps 8
// independent 16B loads in flight per lane. LDS u32[16][260]: pad 260 keeps
// ds_write_b128 16B-aligned at structural-minimum banking; b32 reads are
// 2-way (free). Store phase: g-fast layout -> 4KB contiguous per wave-instr.
__global__ __launch_bounds__(256) void transpose_bf16_v2_kernel(
    const float* __restrict__ x, unsigned short* __restrict__ xT)
{
    __shared__ unsigned int tile[16][260];   // pair index 0..15, col 0..255
    const int t  = threadIdx.x;
    const int i0 = blockIdx.x * 256;

    const int qi = t & 63;       // float4-column 0..63 (fast -> coalesced)
    const int p  = t >> 6;       // row-octet 0..3 (rows 8p .. 8p+7)

    const bool valid_col = (i0 + 4 * qi) < N_IN;   // N_IN % 4 == 0

    if (valid_col) {
        const float* rbase = x + (size_t)(8 * p) * N_IN + i0 + 4 * qi;
        nfloat4 v[8];
#pragma unroll
        for (int j = 0; j < 8; ++j) {
            v[j] = __builtin_nontemporal_load(
                (const nfloat4*)(rbase + (size_t)j * N_IN));
        }
#pragma unroll
        for (int m = 0; m < 4; ++m) {
            // pack rows (8p+2m, 8p+2m+1) -> pair index pm = 4p+m
            uint4 pk;
            pk.x = f32_to_bf16_rne(v[2*m].x) | (f32_to_bf16_rne(v[2*m+1].x) << 16);
            pk.y = f32_to_bf16_rne(v[2*m].y) | (f32_to_bf16_rne(v[2*m+1].y) << 16);
            pk.z = f32_to_bf16_rne(v[2*m].z) | (f32_to_bf16_rne(v[2*m+1].z) << 16);
            pk.w = f32_to_bf16_rne(v[2*m].w) | (f32_to_bf16_rne(v[2*m+1].w) << 16);
            *(uint4*)&tile[4 * p + m][4 * qi] = pk;   // 16B-aligned (1040B rows)
        }
    }
    __syncthreads();

    const int g2 = t & 3;        // 16B chunk within 64B xT row
    const int i2 = t >> 2;       // 0..63
#pragma unroll
    for (int ss = 0; ss < 4; ++ss) {
        const int col  = ss * 64 + i2;        // 0..255
        const int irow = i0 + col;
        if (irow < N_IN) {
            uint4 pk;
            pk.x = tile[4 * g2 + 0][col];
            pk.y = tile[4 * g2 + 1][col];
            pk.z = tile[4 * g2 + 2][col];
            pk.w = tile[4 * g2 + 3][col];
            // cached store: gather re-reads xT; L2/L3 retention is worth it
            *(uint4*)((char*)xT + (size_t)irow * 64 + g2 * 16) = pk;
        }
    }
}

// ---------- Kernel 2 v3: cooperative gather, 2 o's per 4-lane group ----------
// (byte-identical to the verified round-2 version; gather is at the per-XCD
// L2 miss-request-rate cap -> left untouched for clean attribution)
__global__ __launch_bounds__(256, 6) void gather_bf16_v3_kernel(
    const unsigned short* __restrict__ xT,  // (N_IN, 32) bf16
    const float* __restrict__ w,            // (N_OUT, 3)
    const int*   __restrict__ idx,          // (N_OUT, 3)
    float* __restrict__ out)                // (B, N_OUT)
{
    const int t = threadIdx.x;
    const int g = t >> 2;                   // group 0..63
    const int l = t & 3;                    // 16B chunk within 64B row
    const int base0 = blockIdx.x * 128;
    const int oa = base0 + g;
    const int ob = base0 + 64 + g;
    if (oa >= N_OUT) return;
    const bool has_b = (ob < N_OUT);

    const int ba = 3 * oa;
    const int   ia0 = __builtin_nontemporal_load(idx + ba + 0);
    const int   ia1 = __builtin_nontemporal_load(idx + ba + 1);
    const int   ia2 = __builtin_nontemporal_load(idx + ba + 2);
    const float wa0 = __builtin_nontemporal_load(w + ba + 0);
    const float wa1 = __builtin_nontemporal_load(w + ba + 1);
    const float wa2 = __builtin_nontemporal_load(w + ba + 2);

    int   ib0 = 0, ib1 = 0, ib2 = 0;
    float wb0 = 0.f, wb1 = 0.f, wb2 = 0.f;
    if (has_b) {
        const int bb = 3 * ob;
        ib0 = __builtin_nontemporal_load(idx + bb + 0);
        ib1 = __builtin_nontemporal_load(idx + bb + 1);
        ib2 = __builtin_nontemporal_load(idx + bb + 2);
        wb0 = __builtin_nontemporal_load(w + bb + 0);
        wb1 = __builtin_nontemporal_load(w + bb + 1);
        wb2 = __builtin_nontemporal_load(w + bb + 2);
    }

    const uint4 va0 = *(const uint4*)(xT + (size_t)ia0 * B_DIM + l * 8);
    const uint4 va1 = *(const uint4*)(xT + (size_t)ia1 * B_DIM + l * 8);
    const uint4 va2 = *(const uint4*)(xT + (size_t)ia2 * B_DIM + l * 8);
    const uint4 vb0 = *(const uint4*)(xT + (size_t)ib0 * B_DIM + l * 8);
    const uint4 vb1 = *(const uint4*)(xT + (size_t)ib1 * B_DIM + l * 8);
    const uint4 vb2 = *(const uint4*)(xT + (size_t)ib2 * B_DIM + l * 8);

    float acca[8], accb[8];
#pragma unroll
    for (int j = 0; j < 8; ++j) { acca[j] = 0.0f; accb[j] = 0.0f; }

    const unsigned int ua0[4] = {va0.x, va0.y, va0.z, va0.w};
    const unsigned int ua1[4] = {va1.x, va1.y, va1.z, va1.w};
    const unsigned int ua2[4] = {va2.x, va2.y, va2.z, va2.w};
    const unsigned int ub0[4] = {vb0.x, vb0.y, vb0.z, vb0.w};
    const unsigned int ub1[4] = {vb1.x, vb1.y, vb1.z, vb1.w};
    const unsigned int ub2[4] = {vb2.x, vb2.y, vb2.z, vb2.w};
#pragma unroll
    for (int m = 0; m < 4; ++m) {
        float a = acca[2 * m], c = acca[2 * m + 1];
        a = fmaf(wa0, __uint_as_float(ua0[m] << 16), a);
        c = fmaf(wa0, __uint_as_float(ua0[m] & 0xffff0000u), c);
        a = fmaf(wa1, __uint_as_float(ua1[m] << 16), a);
        c = fmaf(wa1, __uint_as_float(ua1[m] & 0xffff0000u), c);
        a = fmaf(wa2, __uint_as_float(ua2[m] << 16), a);
        c = fmaf(wa2, __uint_as_float(ua2[m] & 0xffff0000u), c);
        acca[2 * m] = a; acca[2 * m + 1] = c;

        float d = accb[2 * m], e = accb[2 * m + 1];
        d = fmaf(wb0, __uint_as_float(ub0[m] << 16), d);
        e = fmaf(wb0, __uint_as_float(ub0[m] & 0xffff0000u), e);
        d = fmaf(wb1, __uint_as_float(ub1[m] << 16), d);
        e = fmaf(wb1, __uint_as_float(ub1[m] & 0xffff0000u), e);
        d = fmaf(wb2, __uint_as_float(ub2[m] << 16), d);
        e = fmaf(wb2, __uint_as_float(ub2[m] & 0xffff0000u), e);
        accb[2 * m] = d; accb[2 * m + 1] = e;
    }

    float* obase_a = out + (size_t)(8 * l) * N_OUT + oa;
#pragma unroll
    for (int j = 0; j < 8; ++j) {
        __builtin_nontemporal_store(acca[j], obase_a + (size_t)j * N_OUT);
    }
    if (has_b) {
        float* obase_b = out + (size_t)(8 * l) * N_OUT + ob;
#pragma unroll
        for (int j = 0; j < 8; ++j) {
            __builtin_nontemporal_store(accb[j], obase_b + (size_t)j * N_OUT);
        }
    }
}

// ---------- Fallback (ws too small): direct fp32 gather ----------
__global__ __launch_bounds__(256) void direct_kernel(
    const float* __restrict__ x,
    const float* __restrict__ w,
    const int*   __restrict__ idx,
    float* __restrict__ out)
{
    const int o = blockIdx.x * blockDim.x + threadIdx.x;
    if (o >= N_OUT) return;
    const int base = 3 * o;
    const int i0 = idx[base + 0], i1 = idx[base + 1], i2 = idx[base + 2];
    const float w0 = w[base + 0], w1 = w[base + 1], w2 = w[base + 2];
#pragma unroll 4
    for (int b = 0; b < B_DIM; ++b) {
        const float* __restrict__ xr = x + (size_t)b * N_IN;
        float acc = w0 * xr[i0];
        acc = fmaf(w1, xr[i1], acc);
        acc = fmaf(w2, xr[i2], acc);
        out[(size_t)b * N_OUT + o] = acc;
    }
}

extern "C" void kernel_launch(void* const* d_in, const int* in_sizes, int n_in,
                              void* d_out, int out_size, void* d_ws, size_t ws_size,
                              hipStream_t stream) {
    const float* x   = (const float*)d_in[0];
    const float* w   = (const float*)d_in[1];
    const int*   idx = (const int*)d_in[2];
    float* out = (float*)d_out;

    const size_t xt_bytes = (size_t)N_IN * B_DIM * sizeof(unsigned short); // 64 MB

    if (ws_size >= xt_bytes) {
        unsigned short* xT = (unsigned short*)d_ws;
        const int tblocks = (N_IN + 255) / 256;   // 3907 (tail block: 64 cols)
        transpose_bf16_v2_kernel<<<tblocks, 256, 0, stream>>>(x, xT);
        const int blocks = (N_OUT + 127) / 128;   // 128 o's per block (2 per group)
        gather_bf16_v3_kernel<<<blocks, 256, 0, stream>>>(xT, w, idx, out);
    } else {
        const int blocks = (N_OUT + 255) / 256;
        direct_kernel<<<blocks, 256, 0, stream>>>(x, w, idx, out);
    }
}